// Round 1
// baseline (750.144 us; speedup 1.0000x reference)
//
#include <hip/hip_runtime.h>
#include <math.h>

#define BB 8
#define NN 2048
#define DD 256
#define KK 100
#define RR 5
#define BIGV 1000000000.0f
#define LN_EPS 1e-5f

// ---------------------------------------------------------------------------
// Kernel 1: raw logits S[b,i,j] = sum_d q[b,i,d] * k[b,j,d]  (fp32, NT GEMM)
// 128x128 tile per block, 256 threads, 8x8 accumulator per thread, BK=32.
// ---------------------------------------------------------------------------
__global__ __launch_bounds__(256) void gemm_logits(const float* __restrict__ q,
                                                   const float* __restrict__ k,
                                                   float* __restrict__ s) {
  __shared__ float As[32][132];  // [kk][m], pad keeps float4-aligned rows
  __shared__ float Bs[32][132];
  const int b = blockIdx.z;
  const int i0 = blockIdx.y * 128;
  const int j0 = blockIdx.x * 128;
  const int t = threadIdx.x;
  const int tx = t & 15;
  const int ty = t >> 4;
  const float* qb = q + (size_t)b * NN * DD;
  const float* kb = k + (size_t)b * NN * DD;

  float acc[8][8];
#pragma unroll
  for (int i = 0; i < 8; ++i)
#pragma unroll
    for (int j = 0; j < 8; ++j) acc[i][j] = 0.f;

  for (int kb0 = 0; kb0 < DD; kb0 += 32) {
#pragma unroll
    for (int l = 0; l < 4; ++l) {
      int f = l * 256 + t;
      int row = f >> 3;
      int c4 = (f & 7) * 4;
      float4 va = *(const float4*)(qb + (size_t)(i0 + row) * DD + kb0 + c4);
      float4 vb = *(const float4*)(kb + (size_t)(j0 + row) * DD + kb0 + c4);
      As[c4 + 0][row] = va.x; As[c4 + 1][row] = va.y;
      As[c4 + 2][row] = va.z; As[c4 + 3][row] = va.w;
      Bs[c4 + 0][row] = vb.x; Bs[c4 + 1][row] = vb.y;
      Bs[c4 + 2][row] = vb.z; Bs[c4 + 3][row] = vb.w;
    }
    __syncthreads();
#pragma unroll
    for (int kk = 0; kk < 32; ++kk) {
      float a[8], bv[8];
      *(float4*)&a[0] = *(const float4*)&As[kk][ty * 8];
      *(float4*)&a[4] = *(const float4*)&As[kk][ty * 8 + 4];
      *(float4*)&bv[0] = *(const float4*)&Bs[kk][tx * 8];
      *(float4*)&bv[4] = *(const float4*)&Bs[kk][tx * 8 + 4];
#pragma unroll
      for (int i = 0; i < 8; ++i)
#pragma unroll
        for (int j = 0; j < 8; ++j) acc[i][j] += a[i] * bv[j];
    }
    __syncthreads();
  }

#pragma unroll
  for (int i = 0; i < 8; ++i) {
    size_t row = (size_t)(i0 + ty * 8 + i);
    float* po = s + ((size_t)b * NN + row) * NN + j0 + tx * 8;
    *(float4*)po = make_float4(acc[i][0], acc[i][1], acc[i][2], acc[i][3]);
    *(float4*)(po + 4) = make_float4(acc[i][4], acc[i][5], acc[i][6], acc[i][7]);
  }
}

// ---------------------------------------------------------------------------
// Kernel 2: in-place row softmax over last axis; also emit diagonal prob.
// One block (256 threads) per row; 8 elements per thread as two float4s.
// ---------------------------------------------------------------------------
__device__ inline float pick4(float4 v, int j) {
  return j == 0 ? v.x : (j == 1 ? v.y : (j == 2 ? v.z : v.w));
}

__global__ __launch_bounds__(256) void softmax_rows(float* __restrict__ s,
                                                    float* __restrict__ diag) {
  const int bi = blockIdx.x;          // b*NN + irow
  const int irow = bi & (NN - 1);
  const int t = threadIdx.x;
  float4* rowp = (float4*)(s + (size_t)bi * NN);
  float4 v0 = rowp[t];
  float4 v1 = rowp[256 + t];

  __shared__ float red[4];
  float m = fmaxf(fmaxf(fmaxf(v0.x, v0.y), fmaxf(v0.z, v0.w)),
                  fmaxf(fmaxf(v1.x, v1.y), fmaxf(v1.z, v1.w)));
#pragma unroll
  for (int off = 32; off; off >>= 1) m = fmaxf(m, __shfl_xor(m, off));
  if ((t & 63) == 0) red[t >> 6] = m;
  __syncthreads();
  m = fmaxf(fmaxf(red[0], red[1]), fmaxf(red[2], red[3]));
  __syncthreads();  // red about to be reused

  float4 e0, e1;
  e0.x = expf(v0.x - m); e0.y = expf(v0.y - m);
  e0.z = expf(v0.z - m); e0.w = expf(v0.w - m);
  e1.x = expf(v1.x - m); e1.y = expf(v1.y - m);
  e1.z = expf(v1.z - m); e1.w = expf(v1.w - m);
  float sum = e0.x + e0.y + e0.z + e0.w + e1.x + e1.y + e1.z + e1.w;
#pragma unroll
  for (int off = 32; off; off >>= 1) sum += __shfl_xor(sum, off);
  if ((t & 63) == 0) red[t >> 6] = sum;
  __syncthreads();
  sum = red[0] + red[1] + red[2] + red[3];

  float inv = 1.0f / sum;
  float4 s0 = make_float4(e0.x * inv, e0.y * inv, e0.z * inv, e0.w * inv);
  float4 s1 = make_float4(e1.x * inv, e1.y * inv, e1.z * inv, e1.w * inv);
  rowp[t] = s0;
  rowp[256 + t] = s1;

  int c0 = t * 4;
  if (irow >= c0 && irow < c0 + 4) diag[bi] = pick4(s0, irow - c0);
  int c1 = 1024 + t * 4;
  if (irow >= c1 && irow < c1 + 4) diag[bi] = pick4(s1, irow - c1);
}

// ---------------------------------------------------------------------------
// Kernel 3: per batch, indices of 100 largest diag probs, sorted ascending.
// Tie-break: lower index first (matches jax.lax.top_k).
// ---------------------------------------------------------------------------
__global__ __launch_bounds__(256) void topk_diag(const float* __restrict__ diag,
                                                 int* __restrict__ topidx) {
  const int b = blockIdx.x;
  const int t = threadIdx.x;
  __shared__ float dv[NN];
  __shared__ float rv[4];
  __shared__ int ri[4];
  __shared__ int chosen[KK];
#pragma unroll
  for (int sIt = 0; sIt < 8; ++sIt) dv[t + sIt * 256] = diag[b * NN + t + sIt * 256];
  __syncthreads();

  for (int it = 0; it < KK; ++it) {
    float bv = -1.f;
    int bix = NN;
#pragma unroll
    for (int sIt = 0; sIt < 8; ++sIt) {
      int idx = t + sIt * 256;  // ascending within thread -> strict > keeps lowest
      float v = dv[idx];
      if (v > bv) { bv = v; bix = idx; }
    }
#pragma unroll
    for (int off = 32; off; off >>= 1) {
      float ov = __shfl_xor(bv, off);
      int oi = __shfl_xor(bix, off);
      if (ov > bv || (ov == bv && oi < bix)) { bv = ov; bix = oi; }
    }
    if ((t & 63) == 0) { rv[t >> 6] = bv; ri[t >> 6] = bix; }
    __syncthreads();
    if (t == 0) {
      float fv = rv[0]; int fi = ri[0];
      for (int w = 1; w < 4; ++w)
        if (rv[w] > fv || (rv[w] == fv && ri[w] < fi)) { fv = rv[w]; fi = ri[w]; }
      chosen[it] = fi;
      dv[fi] = -1.f;
    }
    __syncthreads();
  }

  if (t == 0) {
    for (int a2 = 1; a2 < KK; ++a2) {  // insertion sort ascending
      int v = chosen[a2];
      int j = a2 - 1;
      while (j >= 0 && chosen[j] > v) { chosen[j + 1] = chosen[j]; --j; }
      chosen[j + 1] = v;
    }
    for (int a2 = 0; a2 < KK; ++a2) topidx[b * KK + a2] = chosen[a2];
  }
}

// ---------------------------------------------------------------------------
// Kernel 4: rel[i][j] = scores[b, tix[i], tix[j]] (BIG on diag), top-5 per row
// (sorted ascending), emit soi as floats + (subj,obj) pairs for kernel 5.
// ---------------------------------------------------------------------------
__global__ __launch_bounds__(128) void rel_topk(const float* __restrict__ s,
                                                const int* __restrict__ topidx,
                                                float* __restrict__ soi,
                                                int2* __restrict__ pairs) {
  const int b = blockIdx.x;
  const int t = threadIdx.x;
  __shared__ int tix[KK];
  if (t < KK) tix[t] = topidx[b * KK + t];
  __syncthreads();
  if (t >= KK) return;

  const float* rowp = s + ((size_t)b * NN + tix[t]) * NN;
  int sel[RR];
#pragma unroll
  for (int r = 0; r < RR; ++r) sel[r] = -1;
#pragma unroll
  for (int r = 0; r < RR; ++r) {
    float best = -2.f;
    int bj = -1;
    for (int j = 0; j < KK; ++j) {
      bool taken = false;
#pragma unroll
      for (int sN = 0; sN < RR; ++sN)
        if (sN < r && sel[sN] == j) taken = true;
      if (taken) continue;
      float v = (j == t) ? BIGV : rowp[tix[j]];
      if (v > best) { best = v; bj = j; }  // ascending scan + strict > = lower-idx tie-break
    }
    sel[r] = bj;
  }
#pragma unroll
  for (int a2 = 0; a2 < RR; ++a2)
#pragma unroll
    for (int b2 = a2 + 1; b2 < RR; ++b2)
      if (sel[b2] < sel[a2]) { int tmp = sel[a2]; sel[a2] = sel[b2]; sel[b2] = tmp; }

  int subj = tix[t];
#pragma unroll
  for (int r = 0; r < RR; ++r) {
    int obj = tix[sel[r]];
    size_t p = ((size_t)b * KK + t) * RR + r;
    soi[p * 3 + 0] = (float)b;
    soi[p * 3 + 1] = (float)subj;
    soi[p * 3 + 2] = (float)obj;
    pairs[p] = make_int2(subj, obj);
  }
}

// ---------------------------------------------------------------------------
// Kernel 5: re = layernorm(q[b,subj] + q[b,obj]) over D=256. One wave per edge.
// ---------------------------------------------------------------------------
__global__ __launch_bounds__(64) void edge_ln(const float* __restrict__ q,
                                              const int2* __restrict__ pairs,
                                              float* __restrict__ re) {
  const int p = blockIdx.x;
  const int b = p / (KK * RR);
  const int l = threadIdx.x;
  int2 pr = pairs[p];
  const float4* qs = (const float4*)(q + ((size_t)b * NN + pr.x) * DD);
  const float4* qo = (const float4*)(q + ((size_t)b * NN + pr.y) * DD);
  float4 a = qs[l];
  float4 o = qo[l];
  a.x += o.x; a.y += o.y; a.z += o.z; a.w += o.w;
  float sum = a.x + a.y + a.z + a.w;
  float sq = a.x * a.x + a.y * a.y + a.z * a.z + a.w * a.w;
#pragma unroll
  for (int off = 32; off; off >>= 1) {
    sum += __shfl_xor(sum, off);
    sq += __shfl_xor(sq, off);
  }
  float mu = sum * (1.f / DD);
  float var = sq * (1.f / DD) - mu * mu;
  float rs = rsqrtf(var + LN_EPS);
  float4 r4 = make_float4((a.x - mu) * rs, (a.y - mu) * rs,
                          (a.z - mu) * rs, (a.w - mu) * rs);
  ((float4*)(re + (size_t)p * DD))[l] = r4;
}

// ---------------------------------------------------------------------------
extern "C" void kernel_launch(void* const* d_in, const int* in_sizes, int n_in,
                              void* d_out, int out_size, void* d_ws, size_t ws_size,
                              hipStream_t stream) {
  const float* q = (const float*)d_in[0];
  const float* k = (const float*)d_in[1];

  float* out = (float*)d_out;
  float* scores = out;                                    // B*N*N
  float* soi = out + (size_t)BB * NN * NN;                // B*K*R*3 (as floats)
  float* re = soi + (size_t)BB * KK * RR * 3;             // B*K*R*D

  char* ws = (char*)d_ws;
  float* diag = (float*)ws;                               // B*N floats
  int* topidx = (int*)(ws + (size_t)BB * NN * 4);         // B*K ints
  int2* pairs = (int2*)(ws + (size_t)BB * NN * 4 + (size_t)BB * KK * 4);  // B*K*R int2

  gemm_logits<<<dim3(NN / 128, NN / 128, BB), 256, 0, stream>>>(q, k, scores);
  softmax_rows<<<dim3(BB * NN), 256, 0, stream>>>(scores, diag);
  topk_diag<<<dim3(BB), 256, 0, stream>>>(diag, topidx);
  rel_topk<<<dim3(BB), 128, 0, stream>>>(scores, topidx, soi, pairs);
  edge_ln<<<dim3(BB * KK * RR), 64, 0, stream>>>(q, pairs, re);
}

// Round 2
// 494.248 us; speedup vs baseline: 1.5177x; 1.5177x over previous
//
#include <hip/hip_runtime.h>
#include <math.h>

#define BB 8
#define NN 2048
#define DD 256
#define KK 100
#define RR 5
#define BIGV 1000000000.0f
#define LN_EPS 1e-5f

// ---------------------------------------------------------------------------
// Kernel 1: raw logits S[b,i,j] = sum_d q[b,i,d] * k[b,j,d]  (fp32, NT GEMM)
// 128x128 tile per block, 256 threads, 8x8 accumulator per thread, BK=32.
// ---------------------------------------------------------------------------
__global__ __launch_bounds__(256) void gemm_logits(const float* __restrict__ q,
                                                   const float* __restrict__ k,
                                                   float* __restrict__ s) {
  __shared__ float As[32][132];  // [kk][m], pad keeps float4-aligned rows
  __shared__ float Bs[32][132];
  const int b = blockIdx.z;
  const int i0 = blockIdx.y * 128;
  const int j0 = blockIdx.x * 128;
  const int t = threadIdx.x;
  const int tx = t & 15;
  const int ty = t >> 4;
  const float* qb = q + (size_t)b * NN * DD;
  const float* kb = k + (size_t)b * NN * DD;

  float acc[8][8];
#pragma unroll
  for (int i = 0; i < 8; ++i)
#pragma unroll
    for (int j = 0; j < 8; ++j) acc[i][j] = 0.f;

  for (int kb0 = 0; kb0 < DD; kb0 += 32) {
#pragma unroll
    for (int l = 0; l < 4; ++l) {
      int f = l * 256 + t;
      int row = f >> 3;
      int c4 = (f & 7) * 4;
      float4 va = *(const float4*)(qb + (size_t)(i0 + row) * DD + kb0 + c4);
      float4 vb = *(const float4*)(kb + (size_t)(j0 + row) * DD + kb0 + c4);
      As[c4 + 0][row] = va.x; As[c4 + 1][row] = va.y;
      As[c4 + 2][row] = va.z; As[c4 + 3][row] = va.w;
      Bs[c4 + 0][row] = vb.x; Bs[c4 + 1][row] = vb.y;
      Bs[c4 + 2][row] = vb.z; Bs[c4 + 3][row] = vb.w;
    }
    __syncthreads();
#pragma unroll
    for (int kk = 0; kk < 32; ++kk) {
      float a[8], bv[8];
      *(float4*)&a[0] = *(const float4*)&As[kk][ty * 8];
      *(float4*)&a[4] = *(const float4*)&As[kk][ty * 8 + 4];
      *(float4*)&bv[0] = *(const float4*)&Bs[kk][tx * 8];
      *(float4*)&bv[4] = *(const float4*)&Bs[kk][tx * 8 + 4];
#pragma unroll
      for (int i = 0; i < 8; ++i)
#pragma unroll
        for (int j = 0; j < 8; ++j) acc[i][j] += a[i] * bv[j];
    }
    __syncthreads();
  }

#pragma unroll
  for (int i = 0; i < 8; ++i) {
    size_t row = (size_t)(i0 + ty * 8 + i);
    float* po = s + ((size_t)b * NN + row) * NN + j0 + tx * 8;
    *(float4*)po = make_float4(acc[i][0], acc[i][1], acc[i][2], acc[i][3]);
    *(float4*)(po + 4) = make_float4(acc[i][4], acc[i][5], acc[i][6], acc[i][7]);
  }
}

// ---------------------------------------------------------------------------
// Kernel 2: in-place row softmax over last axis; also emit diagonal prob.
// One block (256 threads) per row; 8 elements per thread as two float4s.
// ---------------------------------------------------------------------------
__device__ inline float pick4(float4 v, int j) {
  return j == 0 ? v.x : (j == 1 ? v.y : (j == 2 ? v.z : v.w));
}

__global__ __launch_bounds__(256) void softmax_rows(float* __restrict__ s,
                                                    float* __restrict__ diag) {
  const int bi = blockIdx.x;          // b*NN + irow
  const int irow = bi & (NN - 1);
  const int t = threadIdx.x;
  float4* rowp = (float4*)(s + (size_t)bi * NN);
  float4 v0 = rowp[t];
  float4 v1 = rowp[256 + t];

  __shared__ float red[4];
  float m = fmaxf(fmaxf(fmaxf(v0.x, v0.y), fmaxf(v0.z, v0.w)),
                  fmaxf(fmaxf(v1.x, v1.y), fmaxf(v1.z, v1.w)));
#pragma unroll
  for (int off = 32; off; off >>= 1) m = fmaxf(m, __shfl_xor(m, off));
  if ((t & 63) == 0) red[t >> 6] = m;
  __syncthreads();
  m = fmaxf(fmaxf(red[0], red[1]), fmaxf(red[2], red[3]));
  __syncthreads();  // red about to be reused

  float4 e0, e1;
  e0.x = expf(v0.x - m); e0.y = expf(v0.y - m);
  e0.z = expf(v0.z - m); e0.w = expf(v0.w - m);
  e1.x = expf(v1.x - m); e1.y = expf(v1.y - m);
  e1.z = expf(v1.z - m); e1.w = expf(v1.w - m);
  float sum = e0.x + e0.y + e0.z + e0.w + e1.x + e1.y + e1.z + e1.w;
#pragma unroll
  for (int off = 32; off; off >>= 1) sum += __shfl_xor(sum, off);
  if ((t & 63) == 0) red[t >> 6] = sum;
  __syncthreads();
  sum = red[0] + red[1] + red[2] + red[3];

  float inv = 1.0f / sum;
  float4 s0 = make_float4(e0.x * inv, e0.y * inv, e0.z * inv, e0.w * inv);
  float4 s1 = make_float4(e1.x * inv, e1.y * inv, e1.z * inv, e1.w * inv);
  rowp[t] = s0;
  rowp[256 + t] = s1;

  int c0 = t * 4;
  if (irow >= c0 && irow < c0 + 4) diag[bi] = pick4(s0, irow - c0);
  int c1 = 1024 + t * 4;
  if (irow >= c1 && irow < c1 + 4) diag[bi] = pick4(s1, irow - c1);
}

// ---------------------------------------------------------------------------
// Kernel 3: per batch, indices of 100 largest diag probs, sorted ascending.
// Bitonic sort of packed (valbits<<32 | (NN-1-idx)) keys: value desc, index
// asc on ties -- exactly lax.top_k semantics. Then parallel rank-sort of the
// 100 winning indices into ascending order.
// ---------------------------------------------------------------------------
__global__ __launch_bounds__(1024) void topk_diag(const float* __restrict__ diag,
                                                  int* __restrict__ topidx) {
  const int b = blockIdx.x;
  const int t = threadIdx.x;
  __shared__ unsigned long long key[NN];   // 16 KiB
  __shared__ int idxs[KK];

#pragma unroll
  for (int sIt = 0; sIt < 2; ++sIt) {
    int i = t + sIt * 1024;
    // softmax probs are strictly > 0, so float-bit order == numeric order
    unsigned int vb = __float_as_uint(diag[b * NN + i]);
    key[i] = ((unsigned long long)vb << 32) | (unsigned int)(NN - 1 - i);
  }
  __syncthreads();

  // bitonic sort, descending overall
  for (int kstep = 2; kstep <= NN; kstep <<= 1) {
    for (int j = kstep >> 1; j > 0; j >>= 1) {
      int i = ((t & ~(j - 1)) << 1) | (t & (j - 1));
      int l = i | j;
      unsigned long long a = key[i];
      unsigned long long c = key[l];
      bool desc = ((i & kstep) == 0);
      if (desc ? (a < c) : (a > c)) { key[i] = c; key[l] = a; }
      __syncthreads();
    }
  }

  if (t < KK) idxs[t] = NN - 1 - (int)(unsigned int)(key[t] & 0xFFFFFFFFu);
  __syncthreads();
  if (t < KK) {
    int myidx = idxs[t];
    int rank = 0;
#pragma unroll 4
    for (int j = 0; j < KK; ++j) rank += (idxs[j] < myidx) ? 1 : 0;
    topidx[b * KK + rank] = myidx;   // indices distinct -> ranks unique
  }
}

// ---------------------------------------------------------------------------
// Kernel 4: rel[i][j] = scores[b, tix[i], tix[j]] (BIG on diag), top-5 per row
// (sorted ascending), emit soi as floats + (subj,obj) pairs for kernel 5.
// ---------------------------------------------------------------------------
__global__ __launch_bounds__(128) void rel_topk(const float* __restrict__ s,
                                                const int* __restrict__ topidx,
                                                float* __restrict__ soi,
                                                int2* __restrict__ pairs) {
  const int b = blockIdx.x;
  const int t = threadIdx.x;
  __shared__ int tix[KK];
  if (t < KK) tix[t] = topidx[b * KK + t];
  __syncthreads();
  if (t >= KK) return;

  const float* rowp = s + ((size_t)b * NN + tix[t]) * NN;
  int sel[RR];
#pragma unroll
  for (int r = 0; r < RR; ++r) sel[r] = -1;
#pragma unroll
  for (int r = 0; r < RR; ++r) {
    float best = -2.f;
    int bj = -1;
    for (int j = 0; j < KK; ++j) {
      bool taken = false;
#pragma unroll
      for (int sN = 0; sN < RR; ++sN)
        if (sN < r && sel[sN] == j) taken = true;
      if (taken) continue;
      float v = (j == t) ? BIGV : rowp[tix[j]];
      if (v > best) { best = v; bj = j; }  // ascending scan + strict > = lower-idx tie-break
    }
    sel[r] = bj;
  }
#pragma unroll
  for (int a2 = 0; a2 < RR; ++a2)
#pragma unroll
    for (int b2 = a2 + 1; b2 < RR; ++b2)
      if (sel[b2] < sel[a2]) { int tmp = sel[a2]; sel[a2] = sel[b2]; sel[b2] = tmp; }

  int subj = tix[t];
#pragma unroll
  for (int r = 0; r < RR; ++r) {
    int obj = tix[sel[r]];
    size_t p = ((size_t)b * KK + t) * RR + r;
    soi[p * 3 + 0] = (float)b;
    soi[p * 3 + 1] = (float)subj;
    soi[p * 3 + 2] = (float)obj;
    pairs[p] = make_int2(subj, obj);
  }
}

// ---------------------------------------------------------------------------
// Kernel 5: re = layernorm(q[b,subj] + q[b,obj]) over D=256. One wave per edge.
// ---------------------------------------------------------------------------
__global__ __launch_bounds__(64) void edge_ln(const float* __restrict__ q,
                                              const int2* __restrict__ pairs,
                                              float* __restrict__ re) {
  const int p = blockIdx.x;
  const int b = p / (KK * RR);
  const int l = threadIdx.x;
  int2 pr = pairs[p];
  const float4* qs = (const float4*)(q + ((size_t)b * NN + pr.x) * DD);
  const float4* qo = (const float4*)(q + ((size_t)b * NN + pr.y) * DD);
  float4 a = qs[l];
  float4 o = qo[l];
  a.x += o.x; a.y += o.y; a.z += o.z; a.w += o.w;
  float sum = a.x + a.y + a.z + a.w;
  float sq = a.x * a.x + a.y * a.y + a.z * a.z + a.w * a.w;
#pragma unroll
  for (int off = 32; off; off >>= 1) {
    sum += __shfl_xor(sum, off);
    sq += __shfl_xor(sq, off);
  }
  float mu = sum * (1.f / DD);
  float var = sq * (1.f / DD) - mu * mu;
  float rs = rsqrtf(var + LN_EPS);
  float4 r4 = make_float4((a.x - mu) * rs, (a.y - mu) * rs,
                          (a.z - mu) * rs, (a.w - mu) * rs);
  ((float4*)(re + (size_t)p * DD))[l] = r4;
}

// ---------------------------------------------------------------------------
extern "C" void kernel_launch(void* const* d_in, const int* in_sizes, int n_in,
                              void* d_out, int out_size, void* d_ws, size_t ws_size,
                              hipStream_t stream) {
  const float* q = (const float*)d_in[0];
  const float* k = (const float*)d_in[1];

  float* out = (float*)d_out;
  float* scores = out;                                    // B*N*N
  float* soi = out + (size_t)BB * NN * NN;                // B*K*R*3 (as floats)
  float* re = soi + (size_t)BB * KK * RR * 3;             // B*K*R*D

  char* ws = (char*)d_ws;
  float* diag = (float*)ws;                               // B*N floats
  int* topidx = (int*)(ws + (size_t)BB * NN * 4);         // B*K ints
  int2* pairs = (int2*)(ws + (size_t)BB * NN * 4 + (size_t)BB * KK * 4);  // B*K*R int2

  gemm_logits<<<dim3(NN / 128, NN / 128, BB), 256, 0, stream>>>(q, k, scores);
  softmax_rows<<<dim3(BB * NN), 256, 0, stream>>>(scores, diag);
  topk_diag<<<dim3(BB), 1024, 0, stream>>>(diag, topidx);
  rel_topk<<<dim3(BB), 128, 0, stream>>>(scores, topidx, soi, pairs);
  edge_ln<<<dim3(BB * KK * RR), 64, 0, stream>>>(q, pairs, re);
}

// Round 3
// 326.697 us; speedup vs baseline: 2.2961x; 1.5129x over previous
//
#include <hip/hip_runtime.h>
#include <math.h>

#define BB 8
#define NN 2048
#define DD 256
#define KK 100
#define RR 5
#define BIGV 1000000000.0f
#define LN_EPS 1e-5f

typedef __attribute__((ext_vector_type(8))) short short8;
typedef __attribute__((ext_vector_type(4))) float floatx4;

// ---------------------------------------------------------------------------
// bf16 helpers (manual RNE to avoid header API variance)
// ---------------------------------------------------------------------------
__device__ static inline unsigned short f2bf_rne(float x) {
  unsigned int u = __float_as_uint(x);
  unsigned int r = (u + 0x7FFFu + ((u >> 16) & 1u)) >> 16;
  return (unsigned short)r;
}
__device__ static inline float bf2f(unsigned short h) {
  return __uint_as_float(((unsigned int)h) << 16);
}

__device__ static inline void gl_lds16(const unsigned short* g, unsigned short* l) {
  __builtin_amdgcn_global_load_lds(
      (const __attribute__((address_space(1))) unsigned int*)(g),
      (__attribute__((address_space(3))) unsigned int*)(l), 16, 0, 0);
}

// ---------------------------------------------------------------------------
// Kernel 0: split q,k (fp32) into bf16 hi/lo planes. hi = RNE(x), lo = RNE(x-hi).
// ---------------------------------------------------------------------------
__global__ __launch_bounds__(256) void split_bf16(const float* __restrict__ q,
                                                  const float* __restrict__ k,
                                                  ushort4* __restrict__ qhi,
                                                  ushort4* __restrict__ qlo,
                                                  ushort4* __restrict__ khi,
                                                  ushort4* __restrict__ klo) {
  const int n4 = BB * NN * DD / 4;
  const float4* src = (blockIdx.y == 0) ? (const float4*)q : (const float4*)k;
  ushort4* hi = blockIdx.y ? khi : qhi;
  ushort4* lo = blockIdx.y ? klo : qlo;
  for (int i = blockIdx.x * 256 + threadIdx.x; i < n4; i += gridDim.x * 256) {
    float4 v = src[i];
    ushort4 h, l;
    h.x = f2bf_rne(v.x); l.x = f2bf_rne(v.x - bf2f(h.x));
    h.y = f2bf_rne(v.y); l.y = f2bf_rne(v.y - bf2f(h.y));
    h.z = f2bf_rne(v.z); l.z = f2bf_rne(v.z - bf2f(h.z));
    h.w = f2bf_rne(v.w); l.w = f2bf_rne(v.w - bf2f(h.w));
    hi[i] = h; lo[i] = l;
  }
}

// ---------------------------------------------------------------------------
// Kernel 1: logits via MFMA with 3-term bf16 split.
// 128x128 tile per block, 4 waves (2x2 of 64x64), BK=32, 16x16x32 bf16 MFMA.
// LDS holds fragment-ordered tiles staged directly by global_load_lds x16:
// frag-tile f (16 rows x 32 k) in lane order: lane L <-> A[m=L&15][k=(L>>4)*8..+8].
// Wave w stages plane w (0=Ah,1=Al,2=Bh,3=Bl), frag r=0..7.
// ---------------------------------------------------------------------------
__global__ __launch_bounds__(256) void gemm_mfma_split(
    const unsigned short* __restrict__ qhi, const unsigned short* __restrict__ qlo,
    const unsigned short* __restrict__ khi, const unsigned short* __restrict__ klo,
    float* __restrict__ s) {
  __shared__ unsigned short lds[4][8][512];  // 32 KiB
  const int b = blockIdx.z;
  const int i0 = blockIdx.y * 128, j0 = blockIdx.x * 128;
  const int t = threadIdx.x;
  const int w = t >> 6, L = t & 63;
  const int wx = w & 1, wy = w >> 1;
  const int q_ = L >> 4, m_ = L & 15;

  const size_t bofs = (size_t)b * NN * DD;
  const unsigned short* base;
  {
    const unsigned short* bases0 = qhi + bofs;
    const unsigned short* bases1 = qlo + bofs;
    const unsigned short* bases2 = khi + bofs;
    const unsigned short* bases3 = klo + bofs;
    base = (w == 0) ? bases0 : (w == 1) ? bases1 : (w == 2) ? bases2 : bases3;
  }
  const int rowbase = (w < 2 ? i0 : j0);

  floatx4 acc[4][4];
#pragma unroll
  for (int i = 0; i < 4; ++i)
#pragma unroll
    for (int j = 0; j < 4; ++j) acc[i][j] = (floatx4){0.f, 0.f, 0.f, 0.f};

  for (int kb0 = 0; kb0 < DD; kb0 += 32) {
#pragma unroll
    for (int r = 0; r < 8; ++r) {
      const unsigned short* gp =
          base + (size_t)(rowbase + r * 16 + m_) * DD + kb0 + q_ * 8;
      gl_lds16(gp, &lds[w][r][0]);
    }
    __syncthreads();

    short8 ah[4], al[4], bh[4], bl[4];
#pragma unroll
    for (int i = 0; i < 4; ++i) {
      ah[i] = *(const short8*)&lds[0][wy * 4 + i][L * 8];
      al[i] = *(const short8*)&lds[1][wy * 4 + i][L * 8];
      bh[i] = *(const short8*)&lds[2][wx * 4 + i][L * 8];
      bl[i] = *(const short8*)&lds[3][wx * 4 + i][L * 8];
    }
#pragma unroll
    for (int i = 0; i < 4; ++i)
#pragma unroll
      for (int j = 0; j < 4; ++j) {
        acc[i][j] = __builtin_amdgcn_mfma_f32_16x16x32_bf16(ah[i], bh[j], acc[i][j], 0, 0, 0);
        acc[i][j] = __builtin_amdgcn_mfma_f32_16x16x32_bf16(ah[i], bl[j], acc[i][j], 0, 0, 0);
        acc[i][j] = __builtin_amdgcn_mfma_f32_16x16x32_bf16(al[i], bh[j], acc[i][j], 0, 0, 0);
      }
    __syncthreads();
  }

  // C/D layout (m89-verified): col = lane&15, row = (lane>>4)*4 + reg
#pragma unroll
  for (int i = 0; i < 4; ++i)
#pragma unroll
    for (int j = 0; j < 4; ++j)
#pragma unroll
      for (int r = 0; r < 4; ++r) {
        int row = i0 + wy * 64 + i * 16 + q_ * 4 + r;
        int col = j0 + wx * 64 + j * 16 + m_;
        s[((size_t)b * NN + row) * NN + col] = acc[i][j][r];
      }
}

// ---------------------------------------------------------------------------
// Kernel 1-fallback: fp32 vector GEMM (used only if ws too small for splits).
// ---------------------------------------------------------------------------
__global__ __launch_bounds__(256) void gemm_logits(const float* __restrict__ q,
                                                   const float* __restrict__ k,
                                                   float* __restrict__ s) {
  __shared__ float As[32][132];
  __shared__ float Bs[32][132];
  const int b = blockIdx.z;
  const int i0 = blockIdx.y * 128;
  const int j0 = blockIdx.x * 128;
  const int t = threadIdx.x;
  const int tx = t & 15;
  const int ty = t >> 4;
  const float* qb = q + (size_t)b * NN * DD;
  const float* kb = k + (size_t)b * NN * DD;

  float acc[8][8];
#pragma unroll
  for (int i = 0; i < 8; ++i)
#pragma unroll
    for (int j = 0; j < 8; ++j) acc[i][j] = 0.f;

  for (int kb0 = 0; kb0 < DD; kb0 += 32) {
#pragma unroll
    for (int l = 0; l < 4; ++l) {
      int f = l * 256 + t;
      int row = f >> 3;
      int c4 = (f & 7) * 4;
      float4 va = *(const float4*)(qb + (size_t)(i0 + row) * DD + kb0 + c4);
      float4 vb = *(const float4*)(kb + (size_t)(j0 + row) * DD + kb0 + c4);
      As[c4 + 0][row] = va.x; As[c4 + 1][row] = va.y;
      As[c4 + 2][row] = va.z; As[c4 + 3][row] = va.w;
      Bs[c4 + 0][row] = vb.x; Bs[c4 + 1][row] = vb.y;
      Bs[c4 + 2][row] = vb.z; Bs[c4 + 3][row] = vb.w;
    }
    __syncthreads();
#pragma unroll
    for (int kk = 0; kk < 32; ++kk) {
      float a[8], bv[8];
      *(float4*)&a[0] = *(const float4*)&As[kk][ty * 8];
      *(float4*)&a[4] = *(const float4*)&As[kk][ty * 8 + 4];
      *(float4*)&bv[0] = *(const float4*)&Bs[kk][tx * 8];
      *(float4*)&bv[4] = *(const float4*)&Bs[kk][tx * 8 + 4];
#pragma unroll
      for (int i = 0; i < 8; ++i)
#pragma unroll
        for (int j = 0; j < 8; ++j) acc[i][j] += a[i] * bv[j];
    }
    __syncthreads();
  }

#pragma unroll
  for (int i = 0; i < 8; ++i) {
    size_t row = (size_t)(i0 + ty * 8 + i);
    float* po = s + ((size_t)b * NN + row) * NN + j0 + tx * 8;
    *(float4*)po = make_float4(acc[i][0], acc[i][1], acc[i][2], acc[i][3]);
    *(float4*)(po + 4) = make_float4(acc[i][4], acc[i][5], acc[i][6], acc[i][7]);
  }
}

// ---------------------------------------------------------------------------
// Kernel 2: in-place row softmax; emits diagonal prob.
// ---------------------------------------------------------------------------
__device__ inline float pick4(float4 v, int j) {
  return j == 0 ? v.x : (j == 1 ? v.y : (j == 2 ? v.z : v.w));
}

__global__ __launch_bounds__(256) void softmax_rows(float* __restrict__ s,
                                                    float* __restrict__ diag) {
  const int bi = blockIdx.x;
  const int irow = bi & (NN - 1);
  const int t = threadIdx.x;
  float4* rowp = (float4*)(s + (size_t)bi * NN);
  float4 v0 = rowp[t];
  float4 v1 = rowp[256 + t];

  __shared__ float red[4];
  float m = fmaxf(fmaxf(fmaxf(v0.x, v0.y), fmaxf(v0.z, v0.w)),
                  fmaxf(fmaxf(v1.x, v1.y), fmaxf(v1.z, v1.w)));
#pragma unroll
  for (int off = 32; off; off >>= 1) m = fmaxf(m, __shfl_xor(m, off));
  if ((t & 63) == 0) red[t >> 6] = m;
  __syncthreads();
  m = fmaxf(fmaxf(red[0], red[1]), fmaxf(red[2], red[3]));
  __syncthreads();

  float4 e0, e1;
  e0.x = expf(v0.x - m); e0.y = expf(v0.y - m);
  e0.z = expf(v0.z - m); e0.w = expf(v0.w - m);
  e1.x = expf(v1.x - m); e1.y = expf(v1.y - m);
  e1.z = expf(v1.z - m); e1.w = expf(v1.w - m);
  float sum = e0.x + e0.y + e0.z + e0.w + e1.x + e1.y + e1.z + e1.w;
#pragma unroll
  for (int off = 32; off; off >>= 1) sum += __shfl_xor(sum, off);
  if ((t & 63) == 0) red[t >> 6] = sum;
  __syncthreads();
  sum = red[0] + red[1] + red[2] + red[3];

  float inv = 1.0f / sum;
  float4 s0 = make_float4(e0.x * inv, e0.y * inv, e0.z * inv, e0.w * inv);
  float4 s1 = make_float4(e1.x * inv, e1.y * inv, e1.z * inv, e1.w * inv);
  rowp[t] = s0;
  rowp[256 + t] = s1;

  int c0 = t * 4;
  if (irow >= c0 && irow < c0 + 4) diag[bi] = pick4(s0, irow - c0);
  int c1 = 1024 + t * 4;
  if (irow >= c1 && irow < c1 + 4) diag[bi] = pick4(s1, irow - c1);
}

// ---------------------------------------------------------------------------
// Kernel 3: top-100 of diag per batch via bitonic sort of packed keys.
// ---------------------------------------------------------------------------
__global__ __launch_bounds__(1024) void topk_diag(const float* __restrict__ diag,
                                                  int* __restrict__ topidx) {
  const int b = blockIdx.x;
  const int t = threadIdx.x;
  __shared__ unsigned long long key[NN];
  __shared__ int idxs[KK];

#pragma unroll
  for (int sIt = 0; sIt < 2; ++sIt) {
    int i = t + sIt * 1024;
    unsigned int vb = __float_as_uint(diag[b * NN + i]);
    key[i] = ((unsigned long long)vb << 32) | (unsigned int)(NN - 1 - i);
  }
  __syncthreads();

  for (int kstep = 2; kstep <= NN; kstep <<= 1) {
    for (int j = kstep >> 1; j > 0; j >>= 1) {
      int i = ((t & ~(j - 1)) << 1) | (t & (j - 1));
      int l = i | j;
      unsigned long long a = key[i];
      unsigned long long c = key[l];
      bool desc = ((i & kstep) == 0);
      if (desc ? (a < c) : (a > c)) { key[i] = c; key[l] = a; }
      __syncthreads();
    }
  }

  if (t < KK) idxs[t] = NN - 1 - (int)(unsigned int)(key[t] & 0xFFFFFFFFu);
  __syncthreads();
  if (t < KK) {
    int myidx = idxs[t];
    int rank = 0;
#pragma unroll 4
    for (int j = 0; j < KK; ++j) rank += (idxs[j] < myidx) ? 1 : 0;
    topidx[b * KK + rank] = myidx;
  }
}

// ---------------------------------------------------------------------------
// Kernel 4: gather rel (100x100) into LDS cooperatively, then per-row top-5.
// ---------------------------------------------------------------------------
__global__ __launch_bounds__(256) void rel_topk(const float* __restrict__ s,
                                                const int* __restrict__ topidx,
                                                float* __restrict__ soi,
                                                int2* __restrict__ pairs) {
  const int b = blockIdx.x;
  const int t = threadIdx.x;
  __shared__ int tix[KK];
  __shared__ float rel[KK][KK + 1];  // stride 101 breaks bank aliasing
  if (t < KK) tix[t] = topidx[b * KK + t];
  __syncthreads();

  for (int e = t; e < KK * KK; e += 256) {
    int i = e / KK;
    int j = e - i * KK;
    rel[i][j] = (i == j) ? BIGV : s[((size_t)b * NN + tix[i]) * NN + tix[j]];
  }
  __syncthreads();

  if (t < KK) {
    int sel[RR];
#pragma unroll
    for (int r = 0; r < RR; ++r) sel[r] = -1;
#pragma unroll
    for (int r = 0; r < RR; ++r) {
      float best = -2.f;
      int bj = -1;
      for (int j = 0; j < KK; ++j) {
        bool taken = false;
#pragma unroll
        for (int sN = 0; sN < RR; ++sN)
          if (sN < r && sel[sN] == j) taken = true;
        if (taken) continue;
        float v = rel[t][j];
        if (v > best) { best = v; bj = j; }  // ascending + strict > = lax.top_k tie-break
      }
      sel[r] = bj;
    }
#pragma unroll
    for (int a2 = 0; a2 < RR; ++a2)
#pragma unroll
      for (int b2 = a2 + 1; b2 < RR; ++b2)
        if (sel[b2] < sel[a2]) { int tmp = sel[a2]; sel[a2] = sel[b2]; sel[b2] = tmp; }

    int subj = tix[t];
#pragma unroll
    for (int r = 0; r < RR; ++r) {
      int obj = tix[sel[r]];
      size_t p = ((size_t)b * KK + t) * RR + r;
      soi[p * 3 + 0] = (float)b;
      soi[p * 3 + 1] = (float)subj;
      soi[p * 3 + 2] = (float)obj;
      pairs[p] = make_int2(subj, obj);
    }
  }
}

// ---------------------------------------------------------------------------
// Kernel 5: re = layernorm(q[b,subj] + q[b,obj]) over D=256. One wave per edge.
// ---------------------------------------------------------------------------
__global__ __launch_bounds__(64) void edge_ln(const float* __restrict__ q,
                                              const int2* __restrict__ pairs,
                                              float* __restrict__ re) {
  const int p = blockIdx.x;
  const int b = p / (KK * RR);
  const int l = threadIdx.x;
  int2 pr = pairs[p];
  const float4* qs = (const float4*)(q + ((size_t)b * NN + pr.x) * DD);
  const float4* qo = (const float4*)(q + ((size_t)b * NN + pr.y) * DD);
  float4 a = qs[l];
  float4 o = qo[l];
  a.x += o.x; a.y += o.y; a.z += o.z; a.w += o.w;
  float sum = a.x + a.y + a.z + a.w;
  float sq = a.x * a.x + a.y * a.y + a.z * a.z + a.w * a.w;
#pragma unroll
  for (int off = 32; off; off >>= 1) {
    sum += __shfl_xor(sum, off);
    sq += __shfl_xor(sq, off);
  }
  float mu = sum * (1.f / DD);
  float var = sq * (1.f / DD) - mu * mu;
  float rs = rsqrtf(var + LN_EPS);
  float4 r4 = make_float4((a.x - mu) * rs, (a.y - mu) * rs,
                          (a.z - mu) * rs, (a.w - mu) * rs);
  ((float4*)(re + (size_t)p * DD))[l] = r4;
}

// ---------------------------------------------------------------------------
extern "C" void kernel_launch(void* const* d_in, const int* in_sizes, int n_in,
                              void* d_out, int out_size, void* d_ws, size_t ws_size,
                              hipStream_t stream) {
  const float* q = (const float*)d_in[0];
  const float* k = (const float*)d_in[1];

  float* out = (float*)d_out;
  float* scores = out;                                    // B*N*N
  float* soi = out + (size_t)BB * NN * NN;                // B*K*R*3
  float* re = soi + (size_t)BB * KK * RR * 3;             // B*K*R*D

  char* ws = (char*)d_ws;
  float* diag = (float*)ws;                               // 64 KiB
  int* topidx = (int*)(ws + (size_t)BB * NN * 4);
  int2* pairs = (int2*)(ws + (size_t)BB * NN * 4 + (size_t)BB * KK * 4);
  const size_t small_end = 128 * 1024;                    // small region rounded up
  const size_t plane = (size_t)BB * NN * DD * 2;          // 8 MiB per bf16 plane
  const bool use_mfma = ws_size >= small_end + 4 * plane;

  if (use_mfma) {
    unsigned short* qhi = (unsigned short*)(ws + small_end);
    unsigned short* qlo = (unsigned short*)(ws + small_end + plane);
    unsigned short* khi = (unsigned short*)(ws + small_end + 2 * plane);
    unsigned short* klo = (unsigned short*)(ws + small_end + 3 * plane);
    split_bf16<<<dim3(1024, 2), 256, 0, stream>>>(q, k, (ushort4*)qhi, (ushort4*)qlo,
                                                  (ushort4*)khi, (ushort4*)klo);
    gemm_mfma_split<<<dim3(NN / 128, NN / 128, BB), 256, 0, stream>>>(qhi, qlo, khi, klo,
                                                                      scores);
  } else {
    gemm_logits<<<dim3(NN / 128, NN / 128, BB), 256, 0, stream>>>(q, k, scores);
  }
  softmax_rows<<<dim3(BB * NN), 256, 0, stream>>>(scores, diag);
  topk_diag<<<dim3(BB), 1024, 0, stream>>>(diag, topidx);
  rel_topk<<<dim3(BB), 256, 0, stream>>>(scores, topidx, soi, pairs);
  edge_ln<<<dim3(BB * KK * RR), 64, 0, stream>>>(q, pairs, re);
}